// Round 10
// baseline (577.829 us; speedup 1.0000x reference)
//
#include <hip/hip_runtime.h>
#include <cstdint>
#include <cstddef>

// VQ-VAE vector quantizer forward, MI355X.
// B=65536 rows, K=4096 codes, D=256.
// Outputs (flat float32): z_q_st[B*D] | vq_loss | perplexity | indices[B] | diversity_loss

#define NROWS     65536
#define NCODES    4096
#define DDIM      256
#define CAP_H     10      // candidate slots per (row, wn-half)
#define CAND_STRIDE 20    // ints per row in cand_idx
#define UMARGIN   1.0f    // u-space: d-margin 2.0 / 2
#define USKIP     8.5f    // u-space: d-skip 17 / 2 (dropped soft terms < e^-17, Z>=1)

typedef _Float16 half8 __attribute__((ext_vector_type(8)));
typedef _Float16 half4 __attribute__((ext_vector_type(4)));
typedef float    f32x4 __attribute__((ext_vector_type(4)));

// ---- workspace layout (bytes) ----
#define WS_BINCNT   0u          // 4096*4     = 16384    (zeroed)
#define WS_ZERO_END 16384u
#define WS_CANDCNT  16384u      // 65536*2*4  = 524288   (fully written by sweep)
#define WS_SPART    540672u     // 512*4096*4 = 8388608  (fully written by sweep)
#define WS_EF16     8929280u    // 4096*256*2 = 2097152
#define WS_EE       11026432u   // 4096*4     = 16384
#define WS_ROWD     11042816u   // 65536*4    = 262144
#define WS_CANDIDX  11304960u   // 65536*20*4 = 5242880  (aliased as tm[4096] dbl after refine)
#define WS_TE       16547840u   // 4096*8     = 32768
#define WS_TP       16580608u   // 4096*8     = 32768
#define WS_END      16613376u

__device__ __forceinline__ void gload_lds16(const void* g, void* lds) {
    __builtin_amdgcn_global_load_lds(
        (const __attribute__((address_space(1))) unsigned int*)g,
        (__attribute__((address_space(3))) unsigned int*)lds, 16, 0, 0);
}

// ---------------- prep (embedding only): fp32 -> fp16 copy + row norms ----------------
__global__ __launch_bounds__(256)
void prep_kernel(const float* __restrict__ src, _Float16* __restrict__ dst,
                 float* __restrict__ norms)
{
    const int tid = threadIdx.x;
    const int w = tid >> 6, l = tid & 63;
    const int row = blockIdx.x * 4 + w;
    const float4 v = *(const float4*)(src + (size_t)row * DDIM + l * 4);
    half4 h;
    h[0] = (_Float16)v.x; h[1] = (_Float16)v.y;
    h[2] = (_Float16)v.z; h[3] = (_Float16)v.w;
    *(half4*)(dst + (size_t)row * DDIM + l * 4) = h;
    double s = (double)v.x * v.x + (double)v.y * v.y
             + (double)v.z * v.z + (double)v.w * v.w;
#pragma unroll
    for (int off = 1; off < 64; off <<= 1) s += __shfl_xor(s, off, 64);
    if (l == 0) norms[row] = (float)s;
}

// ---------------- fused two-phase distance sweep, double-buffered ----------------
// Block: 128 rows x all 4096 codes. 4 waves = 2 M-groups (wm: 64 rows, fr=0..3)
//        x 2 N-groups (wn: 32 of the 64 tile codes, cf=0..1).
// The two wn-waves SHARE rows, so all per-row state is partitioned by wn:
//  - candidates: cand_cnt[row*2+wn], cand_idx[row*20 + wn*10 + slot] (no collisions)
//  - softmax (m,Z): per-wave half-stats merged ACROSS wn via the Sl LDS buffer at
//    the phase boundary (Sl[0..511] is still zero there; re-zeroed after merge).
// B: 64-code x K=256 sub-tiles, 2 x 32 KB LDS dbuf, FRAGMENT-MAJOR (lane-linear
// conflict-free ds_read_b128; staged via global_load_lds with pre-permuted source).
// u-space epilogue: acc init = -0.5*||e||^2 so MFMA emits u = -d'/2 directly.
// eev pipelined one step ahead; no mid-loop vmcnt(0); ballot candidates, no atomics.
// Phase 0 (s 0..63): exact online (max u, Z), defer-rescale, skip-far exp.
// Phase 1 (s 64..127): identical u (same init+MFMA chain); soft partials; candidates.
__global__ __attribute__((amdgpu_flat_work_group_size(256, 256), amdgpu_waves_per_eu(2, 2)))
void sweep_fused_kernel(const float* __restrict__ z, const _Float16* __restrict__ ef,
                        const float* __restrict__ ee, float* __restrict__ Spart,
                        int* __restrict__ cand_cnt, int* __restrict__ cand_idx)
{
    __shared__ _Float16 Bl[2][64 * 256];   // 2 x 32 KB, fragment-major
    __shared__ float Sl[NCODES];           // 16 KB soft accumulator (+ phase-boundary exchange)

    const int tid = threadIdx.x;
    const int w = tid >> 6, l = tid & 63;
    const int wm = w & 1, wn = w >> 1;
    const int lg = l >> 4, lc = l & 15;
    const int row0 = blockIdx.x * 128;

    // A fragments: row = row0 + wm*64 + fr*16 + lc, k = ksl*32 + lg*8 .. +8 (f32 -> f16)
    half8 af[4][8];
#pragma unroll
    for (int fr = 0; fr < 4; ++fr)
#pragma unroll
    for (int ksl = 0; ksl < 8; ++ksl) {
        const float* zp = z + (size_t)(row0 + wm * 64 + fr * 16 + lc) * DDIM + ksl * 32 + lg * 8;
        const float4 v0 = *(const float4*)zp;
        const float4 v1 = *(const float4*)(zp + 4);
        half8 h;
        h[0] = (_Float16)v0.x; h[1] = (_Float16)v0.y; h[2] = (_Float16)v0.z; h[3] = (_Float16)v0.w;
        h[4] = (_Float16)v1.x; h[5] = (_Float16)v1.y; h[6] = (_Float16)v1.z; h[7] = (_Float16)v1.w;
        af[fr][ksl] = h;
    }

    for (int i = tid; i < NCODES; i += 256) Sl[i] = 0.0f;

    // staging: instr it_g = w*8+it = slot (ksl=it_g>>2, cf=it_g&3); lane l fetches
    // global code cf*16+lc at kbytes ksl*64+lg*16 -> LDS it_g*1024 + l*16 (linear).
    int soff[8];
#pragma unroll
    for (int it = 0; it < 8; ++it) {
        const int it_g = w * 8 + it;
        const int ksl = it_g >> 2, cf = it_g & 3;
        soff[it] = (cf * 16 + lc) * 512 + ksl * 64 + lg * 16;
    }
    const char* efb = (const char*)ef;
    char* blb = (char*)&Bl[0][0];

    float pmx[16], pZ[16];
#pragma unroll
    for (int i = 0; i < 16; ++i) { pmx[i] = -1e30f; pZ[i] = 0.0f; }
    int bcnt[16];
#pragma unroll
    for (int i = 0; i < 16; ++i) bcnt[i] = 0;

    // prologue: eev for tile 0 + stage tile 0 into buffer 0
    float eevc[2];
#pragma unroll
    for (int cf = 0; cf < 2; ++cf) eevc[cf] = ee[(wn * 2 + cf) * 16 + lc];
#pragma unroll
    for (int it = 0; it < 8; ++it)
        gload_lds16(efb + soff[it], blb + (w * 8 + it) * 1024);
    __syncthreads();

    for (int s = 0; s < 128; ++s) {
        const int cur = s & 1;
        const int nt = s & 63;
        const int nnt = (s + 1) & 63;

        if (s == 64) {
            // phase boundary, part 2: merge with partner wave's half-(m,Z) from Sl
            // (published at s==63 and barrier-protected; Sl accumulation not started).
#pragma unroll
            for (int fr = 0; fr < 4; ++fr)
#pragma unroll
            for (int reg = 0; reg < 4; ++reg) {
                const int ri = fr * 4 + reg;
                const int rb = wm * 64 + fr * 16 + lg * 4 + reg;
                const float m2 = Sl[(wn ^ 1) * 128 + rb];
                const float Z2 = Sl[256 + (wn ^ 1) * 128 + rb];
                const float m1 = pmx[ri], Z1 = pZ[ri];
                const float mn = fmaxf(m1, m2);
                const float Zt = Z1 * __expf(2.0f * (m1 - mn)) + Z2 * __expf(2.0f * (m2 - mn));
                pmx[ri] = mn;
                pZ[ri] = 1.0f / Zt;
            }
            __syncthreads();                       // all merge reads complete
            if (tid < 512) Sl[tid] = 0.0f;         // restore accumulator zeros
            __syncthreads();
        }

        // next-step eev: issued now, consumed after the barrier (never waited mid-loop)
        float eevn[2];
#pragma unroll
        for (int cf = 0; cf < 2; ++cf) eevn[cf] = ee[nnt * 64 + (wn * 2 + cf) * 16 + lc];

        if (s < 127) {                      // stage next sub-tile into other buffer
            const char* src = efb + ((size_t)nnt << 15);
            char* dst = blb + (cur ^ 1) * 32768;
#pragma unroll
            for (int it = 0; it < 8; ++it)
                gload_lds16(src + soff[it], dst + (w * 8 + it) * 1024);
        }

        // acc init: -0.5*||e||^2  ->  MFMA output u = z.e - ||e||^2/2 = -d'/2
        const float eh0 = -0.5f * eevc[0], eh1 = -0.5f * eevc[1];
        f32x4 acc[4][2];
#pragma unroll
        for (int fr = 0; fr < 4; ++fr) {
            acc[fr][0] = (f32x4){eh0, eh0, eh0, eh0};
            acc[fr][1] = (f32x4){eh1, eh1, eh1, eh1};
        }

        // lane-linear B reads of this wave's half-tile (conflict-free), imm offsets
        const char* bb = blb + cur * 32768 + (l << 4) + wn * 2048;
        __builtin_amdgcn_s_setprio(1);
#pragma unroll
        for (int ksl = 0; ksl < 8; ++ksl) {
            const half8 b0 = *(const half8*)(bb + (ksl * 4 + 0) * 1024);
            const half8 b1 = *(const half8*)(bb + (ksl * 4 + 1) * 1024);
#pragma unroll
            for (int fr = 0; fr < 4; ++fr) {
                acc[fr][0] = __builtin_amdgcn_mfma_f32_16x16x32_f16(af[fr][ksl], b0, acc[fr][0], 0, 0, 0);
                acc[fr][1] = __builtin_amdgcn_mfma_f32_16x16x32_f16(af[fr][ksl], b1, acc[fr][1], 0, 0, 0);
            }
        }
        __builtin_amdgcn_s_setprio(0);

        if (s < 64) {
            // phase 0: exact online (max u, Z) over this wave's code half
#pragma unroll
            for (int fr = 0; fr < 4; ++fr)
#pragma unroll
            for (int reg = 0; reg < 4; ++reg) {
                const int ri = fr * 4 + reg;
                const float u0 = acc[fr][0][reg];
                const float u1 = acc[fr][1][reg];
                const float mloc = fmaxf(u0, u1);
                float m = pmx[ri];
                if (mloc > m - USKIP) {
                    if (mloc > m) { pZ[ri] *= __expf(2.0f * (m - mloc)); m = mloc; pmx[ri] = m; }
                    pZ[ri] += __expf(2.0f * (u0 - m)) + __expf(2.0f * (u1 - m));
                }
            }
        } else {
            // phase 1: u bitwise identical to phase 0 (same init, same MFMA chain);
            // m,1/Z are now GLOBAL row stats (merged across wn at s==64).
            float sp[2] = {0.f, 0.f};
#pragma unroll
            for (int fr = 0; fr < 4; ++fr)
#pragma unroll
            for (int reg = 0; reg < 4; ++reg) {
                const int ri = fr * 4 + reg;
                const float m = pmx[ri], iz = pZ[ri];
#pragma unroll
                for (int cf = 0; cf < 2; ++cf) {
                    const float u = acc[fr][cf][reg];
                    // candidates: ballot + prefix-popcount slots, per-(row,wn) storage
                    const bool hit = (u >= m - UMARGIN);   // m = global phase-0 row max
                    const unsigned long long mk = __ballot(hit);
                    if (mk) {                              // uniform branch, rare
                        const unsigned grp = (unsigned)((mk >> (lg * 16)) & 0xFFFFull);
                        const int slot = bcnt[ri] + __popc(grp & ((1u << lc) - 1u));
                        if (hit && slot < CAP_H) {
                            const int rg_ = row0 + wm * 64 + fr * 16 + lg * 4 + reg;
                            cand_idx[(size_t)rg_ * CAND_STRIDE + wn * CAP_H + slot]
                                = nt * 64 + (wn * 2 + cf) * 16 + lc;
                        }
                        bcnt[ri] += __popc(grp);
                    }
                    if (u >= m - USKIP) sp[cf] += __expf(2.0f * (u - m)) * iz;
                }
            }
#pragma unroll
            for (int cf = 0; cf < 2; ++cf) {   // sum across lg, then LDS accumulate
                float v = sp[cf];
                v += __shfl_xor(v, 16, 64);
                v += __shfl_xor(v, 32, 64);
                if (l < 16) atomicAdd(&Sl[nt * 64 + (wn * 2 + cf) * 16 + l], v);
            }
        }

        if (s == 63) {
            // phase boundary, part 1: intra-wave merge across the 16 lanes sharing
            // each row, then publish this wave's half-(m,Z) into Sl[0..511].
#pragma unroll
            for (int ri = 0; ri < 16; ++ri) {
                float m = pmx[ri], Zv = pZ[ri];
#pragma unroll
                for (int off = 1; off < 16; off <<= 1) {
                    const float mo = __shfl_xor(m, off, 64);
                    const float Zo = __shfl_xor(Zv, off, 64);
                    const float mn = fmaxf(m, mo);
                    Zv = Zv * __expf(2.0f * (m - mn)) + Zo * __expf(2.0f * (mo - mn));
                    m = mn;
                }
                pmx[ri] = m;
                pZ[ri] = Zv;   // still the half-Z; global merge happens at s==64
            }
            if (lc == 0) {
#pragma unroll
                for (int fr = 0; fr < 4; ++fr)
#pragma unroll
                for (int reg = 0; reg < 4; ++reg) {
                    const int rb = wm * 64 + fr * 16 + lg * 4 + reg;
                    Sl[wn * 128 + rb]       = pmx[fr * 4 + reg];
                    Sl[256 + wn * 128 + rb] = pZ[fr * 4 + reg];
                }
            }
        }

        __syncthreads();   // sole vmcnt drain: staging + eev issued a full phase ago
        eevc[0] = eevn[0]; eevc[1] = eevn[1];
    }

    // final: per-(row, half) candidate counts (plain stores; no cross-wave aliasing)
    if (lc == 0) {
#pragma unroll
        for (int fr = 0; fr < 4; ++fr)
#pragma unroll
        for (int reg = 0; reg < 4; ++reg)
            cand_cnt[(row0 + wm * 64 + fr * 16 + lg * 4 + reg) * 2 + wn] = bcnt[fr * 4 + reg];
    }

    for (int i = tid; i < NCODES; i += 256)
        Spart[(size_t)blockIdx.x * NCODES + i] = Sl[i];
}

// ---------------- refine: exact fp64 argmin over candidate union ----------------
__global__ __launch_bounds__(256)
void refine_kernel(const float* __restrict__ z, const float* __restrict__ emb,
                   const int* __restrict__ cand_cnt, const int* __restrict__ cand_idx,
                   float* __restrict__ out_zq, float* __restrict__ out_idx,
                   unsigned int* __restrict__ bincnt, float* __restrict__ rowD)
{
    const int tid = threadIdx.x;
    const int w = tid >> 6, l = tid & 63;
    const int row = blockIdx.x * 4 + w;
    const float4 zv = *(const float4*)(z + (size_t)row * DDIM + l * 4);
    const double z0 = zv.x, z1 = zv.y, z2 = zv.z, z3 = zv.w;
    int c0 = cand_cnt[row * 2 + 0];
    int c1 = cand_cnt[row * 2 + 1];
    c0 = c0 < 0 ? 0 : (c0 > CAP_H ? CAP_H : c0);
    c1 = c1 < 0 ? 0 : (c1 > CAP_H ? CAP_H : c1);
    double dmin = 1e300; int kmin = 0;
    // seed with code 0, then scan both halves (true argmin is always a stored hit)
    for (int c = -1; c < c0 + c1; ++c) {
        int k = 0;
        if (c >= 0) {
            const int off = (c < c0) ? c : (CAP_H + (c - c0));
            k = cand_idx[(size_t)row * CAND_STRIDE + off] & (NCODES - 1);
        }
        const float4 ev = *(const float4*)(emb + (size_t)k * DDIM + l * 4);
        const double t0 = z0 - ev.x, t1 = z1 - ev.y, t2 = z2 - ev.z, t3 = z3 - ev.w;
        double s = t0 * t0 + t1 * t1 + t2 * t2 + t3 * t3;
#pragma unroll
        for (int off2 = 1; off2 < 64; off2 <<= 1) s += __shfl_xor(s, off2, 64);
        if (s < dmin || (s == dmin && k < kmin)) { dmin = s; kmin = k; }
    }
    const float4 bv = *(const float4*)(emb + (size_t)kmin * DDIM + l * 4);
    *(float4*)(out_zq + (size_t)row * DDIM + l * 4) = bv;   // z + sg(zq - z) == zq
    if (l == 0) {
        out_idx[row] = (float)kmin;
        atomicAdd(&bincnt[kmin], 1u);
        rowD[row] = (float)dmin;                             // dmin == ||z - zq||^2
    }
}

// ---------------- reductions ----------------
__global__ __launch_bounds__(256)
void reduce1_kernel(const float* __restrict__ Spart, const unsigned int* __restrict__ bincnt,
                    const float* __restrict__ rowD,
                    double* __restrict__ te, double* __restrict__ tp, double* __restrict__ tm)
{
    const int k = blockIdx.x * 256 + threadIdx.x;   // grid 16 -> k < 4096
    double s = 0.0;
#pragma unroll 8
    for (int wg = 0; wg < 512; ++wg) s += (double)Spart[(size_t)wg * NCODES + k];
    const double avg = s * (1.0 / 65536.0);
    te[k] = avg * log(avg + 1e-10);
    const double ap = (double)bincnt[k] * (1.0 / 65536.0);
    tp[k] = ap * log(ap + 1e-10);
    double dm = 0.0;
#pragma unroll
    for (int j = 0; j < 16; ++j) dm += (double)rowD[k * 16 + j];
    tm[k] = dm;
}

__global__ __launch_bounds__(256)
void reduce2_kernel(const double* __restrict__ te, const double* __restrict__ tp,
                    const double* __restrict__ tm, float* __restrict__ out)
{
    __shared__ double sa[256], sb[256], sc[256];
    const int tid = threadIdx.x;
    double a = 0.0, b = 0.0, c = 0.0;
    for (int i = tid; i < NCODES; i += 256) { a += te[i]; b += tp[i]; c += tm[i]; }
    sa[tid] = a; sb[tid] = b; sc[tid] = c;
    __syncthreads();
    for (int s = 128; s > 0; s >>= 1) {
        if (tid < s) { sa[tid] += sa[tid + s]; sb[tid] += sb[tid + s]; sc[tid] += sc[tid + s]; }
        __syncthreads();
    }
    if (tid == 0) {
        const double entropy    = -sa[0];
        const double diversity  = log(4096.0) - entropy;
        const double perplexity = exp(-sb[0]);
        const double mse        = sc[0] * (1.0 / 16777216.0);
        const double vq         = 1.25 * mse + 0.1 * diversity;  // 0.25*c + e + 0.1*d, c==e
        out[16777216] = (float)vq;
        out[16777217] = (float)perplexity;
        out[16842754] = (float)diversity;
    }
}

extern "C" void kernel_launch(void* const* d_in, const int* in_sizes, int n_in,
                              void* d_out, int out_size, void* d_ws, size_t ws_size,
                              hipStream_t stream)
{
    const float* z   = (const float*)d_in[0];
    const float* emb = (const float*)d_in[1];
    float* out = (float*)d_out;
    char* ws = (char*)d_ws;
    if (ws_size < (size_t)WS_END) return;   // need ~16.6 MB scratch

    unsigned int* bincnt   = (unsigned int*)(ws + WS_BINCNT);
    int*          cand_cnt = (int*)(ws + WS_CANDCNT);
    float*        Spart    = (float*)(ws + WS_SPART);
    _Float16*     ef16     = (_Float16*)(ws + WS_EF16);
    float*        ee       = (float*)(ws + WS_EE);
    float*        rowD     = (float*)(ws + WS_ROWD);
    int*          cand_idx = (int*)(ws + WS_CANDIDX);
    double*       te       = (double*)(ws + WS_TE);
    double*       tp       = (double*)(ws + WS_TP);
    double*       tm       = (double*)(ws + WS_CANDIDX);  // cand_idx dead after refine

    hipMemsetAsync(d_ws, 0, WS_ZERO_END, stream);   // bincnt only (16 KB)
    hipLaunchKernelGGL(prep_kernel, dim3(NCODES / 4), dim3(256), 0, stream, emb, ef16, ee);
    hipLaunchKernelGGL(sweep_fused_kernel, dim3(NROWS / 128), dim3(256), 0, stream,
                       z, ef16, ee, Spart, cand_cnt, cand_idx);
    hipLaunchKernelGGL(refine_kernel, dim3(NROWS / 4), dim3(256), 0, stream,
                       z, emb, cand_cnt, cand_idx, out, out + 16777218, bincnt, rowD);
    hipLaunchKernelGGL(reduce1_kernel, dim3(16), dim3(256), 0, stream, Spart, bincnt, rowD, te, tp, tm);
    hipLaunchKernelGGL(reduce2_kernel, dim3(1), dim3(256), 0, stream, te, tp, tm, out);
}

// Round 11
// 454.496 us; speedup vs baseline: 1.2714x; 1.2714x over previous
//
#include <hip/hip_runtime.h>
#include <cstdint>
#include <cstddef>

// VQ-VAE vector quantizer forward, MI355X.
// B=65536 rows, K=4096 codes, D=256.
// Outputs (flat float32): z_q_st[B*D] | vq_loss | perplexity | indices[B] | diversity_loss

#define NROWS     65536
#define NCODES    4096
#define DDIM      256
#define CAND_CAP  24
#define UMARGIN   1.0f    // u-space: d-margin 2.0 / 2
#define USKIP     8.5f    // u-space: d-skip 17 / 2 (dropped soft terms < e^-17, Z>=1)

typedef _Float16 half8 __attribute__((ext_vector_type(8)));
typedef _Float16 half4 __attribute__((ext_vector_type(4)));
typedef float    f32x4 __attribute__((ext_vector_type(4)));

// ---- workspace layout (bytes) ----
#define WS_BINCNT   0u          // 4096*4    = 16384    (zeroed)
#define WS_ZERO_END 16384u
#define WS_CANDCNT  16384u      // 65536*4   = 262144   (plain-written by sweep, no zero)
#define WS_SPART    278528u     // 512*4096*4 = 8388608 (fully written by sweep)
#define WS_EF16     8667136u    // 4096*256*2 = 2097152
#define WS_EE       10764288u   // 4096*4     = 16384
#define WS_ROWD     10780672u   // 65536*4    = 262144
#define WS_CANDIDX  11042816u   // 65536*24*4 = 6291456 (aliased as tm[4096] dbl after refine)
#define WS_TE       17334272u   // 4096*8     = 32768
#define WS_TP       17367040u   // 4096*8     = 32768
#define WS_END      17399808u

__device__ __forceinline__ void gload_lds16(const void* g, void* lds) {
    __builtin_amdgcn_global_load_lds(
        (const __attribute__((address_space(1))) unsigned int*)g,
        (__attribute__((address_space(3))) unsigned int*)lds, 16, 0, 0);
}

// ---------------- prep (embedding only): fp32 -> fp16 copy + row norms ----------------
__global__ __launch_bounds__(256)
void prep_kernel(const float* __restrict__ src, _Float16* __restrict__ dst,
                 float* __restrict__ norms)
{
    const int tid = threadIdx.x;
    const int w = tid >> 6, l = tid & 63;
    const int row = blockIdx.x * 4 + w;
    const float4 v = *(const float4*)(src + (size_t)row * DDIM + l * 4);
    half4 h;
    h[0] = (_Float16)v.x; h[1] = (_Float16)v.y;
    h[2] = (_Float16)v.z; h[3] = (_Float16)v.w;
    *(half4*)(dst + (size_t)row * DDIM + l * 4) = h;
    double s = (double)v.x * v.x + (double)v.y * v.y
             + (double)v.z * v.z + (double)v.w * v.w;
#pragma unroll
    for (int off = 1; off < 64; off <<= 1) s += __shfl_xor(s, off, 64);
    if (l == 0) norms[row] = (float)s;
}

// ---------------- fused two-phase distance sweep, double-buffered ----------------
// r7 geometry: 4 waves, wave w owns rows w*32..+31 for ALL codes (no cross-wave
// row sharing -> single candidate list per row, in-wave softmax merge only).
// B: 64-code x K=256 sub-tiles, 2 x 32 KB LDS dbuf, FRAGMENT-MAJOR
// (lane-linear conflict-free ds_read_b128; staged via global_load_lds with
// pre-permuted per-lane global source, rule #21).
// r8 VALU cuts: u-space accumulator init (acc = -0.5*||e||^2, MFMA emits
// u = -d'/2 -> no epilogue fma), eev prefetched one step ahead (no mid-loop
// vmem waits), setprio(1) around the MFMA cluster, ballot candidates (CAP 24,
// prefix-popcount slots, fire-and-forget stores, zero atomics).
// Phase 0 (s 0..63): exact online (max u, Z), defer-rescale, skip-far exp.
// Phase 1 (s 64..127): u bitwise identical (same init + same MFMA chain);
// soft partials into LDS Sl; candidate shortlist (true argmin always a hit).
__global__ __launch_bounds__(256, 2)
void sweep_fused_kernel(const float* __restrict__ z, const _Float16* __restrict__ ef,
                        const float* __restrict__ ee, float* __restrict__ Spart,
                        int* __restrict__ cand_cnt, int* __restrict__ cand_idx)
{
    __shared__ _Float16 Bl[2][64 * 256];   // 2 x 32 KB, fragment-major
    __shared__ float Sl[NCODES];           // 16 KB soft accumulator

    const int tid = threadIdx.x;
    const int w = tid >> 6, l = tid & 63;
    const int lg = l >> 4, lc = l & 15;
    const int row0 = blockIdx.x * 128;

    // A fragments: row = row0 + w*32 + fr*16 + lc, k = ksl*32 + lg*8 .. +8 (f32 -> f16)
    half8 af[2][8];
#pragma unroll
    for (int fr = 0; fr < 2; ++fr)
#pragma unroll
    for (int ksl = 0; ksl < 8; ++ksl) {
        const float* zp = z + (size_t)(row0 + w * 32 + fr * 16 + lc) * DDIM + ksl * 32 + lg * 8;
        const float4 v0 = *(const float4*)zp;
        const float4 v1 = *(const float4*)(zp + 4);
        half8 h;
        h[0] = (_Float16)v0.x; h[1] = (_Float16)v0.y; h[2] = (_Float16)v0.z; h[3] = (_Float16)v0.w;
        h[4] = (_Float16)v1.x; h[5] = (_Float16)v1.y; h[6] = (_Float16)v1.z; h[7] = (_Float16)v1.w;
        af[fr][ksl] = h;
    }

    for (int i = tid; i < NCODES; i += 256) Sl[i] = 0.0f;

    // staging: instr it_g = w*8+it = slot (ksl=it_g>>2, cf=it_g&3); lane l fetches
    // global code cf*16+lc at kbytes ksl*64+lg*16 -> LDS it_g*1024 + l*16 (linear).
    int soff[8];
#pragma unroll
    for (int it = 0; it < 8; ++it) {
        const int it_g = w * 8 + it;
        const int ksl = it_g >> 2, cf = it_g & 3;
        soff[it] = (cf * 16 + lc) * 512 + ksl * 64 + lg * 16;
    }
    const char* efb = (const char*)ef;
    char* blb = (char*)&Bl[0][0];

    float pmx[8], pZ[8];
#pragma unroll
    for (int i = 0; i < 8; ++i) { pmx[i] = -1e30f; pZ[i] = 0.0f; }
    int bcnt[8];
#pragma unroll
    for (int i = 0; i < 8; ++i) bcnt[i] = 0;

    // prologue: eev for tile 0 + stage tile 0 into buffer 0
    float eevc[4];
#pragma unroll
    for (int cf = 0; cf < 4; ++cf) eevc[cf] = ee[cf * 16 + lc];
#pragma unroll
    for (int it = 0; it < 8; ++it)
        gload_lds16(efb + soff[it], blb + (w * 8 + it) * 1024);
    __syncthreads();

    for (int s = 0; s < 128; ++s) {
        const int cur = s & 1;
        const int nt = s & 63;
        const int nnt = (s + 1) & 63;

        // next-step eev: issued now, consumed after the barrier (never waited mid-loop)
        float eevn[4];
#pragma unroll
        for (int cf = 0; cf < 4; ++cf) eevn[cf] = ee[nnt * 64 + cf * 16 + lc];

        if (s < 127) {                      // stage next sub-tile into other buffer
            const char* src = efb + ((size_t)nnt << 15);
            char* dst = blb + (cur ^ 1) * 32768;
#pragma unroll
            for (int it = 0; it < 8; ++it)
                gload_lds16(src + soff[it], dst + (w * 8 + it) * 1024);
        }

        // acc init: -0.5*||e||^2  ->  MFMA output u = z.e - ||e||^2/2 = -d'/2
        f32x4 acc[2][4];
#pragma unroll
        for (int cf = 0; cf < 4; ++cf) {
            const float eh = -0.5f * eevc[cf];
            acc[0][cf] = (f32x4){eh, eh, eh, eh};
            acc[1][cf] = (f32x4){eh, eh, eh, eh};
        }

        // lane-linear B reads (conflict-free), immediate offsets
        const char* bb = blb + cur * 32768 + (l << 4);
        __builtin_amdgcn_s_setprio(1);
#pragma unroll
        for (int ksl = 0; ksl < 8; ++ksl) {
#pragma unroll
            for (int cf = 0; cf < 4; ++cf) {
                const half8 b = *(const half8*)(bb + (ksl * 4 + cf) * 1024);
                acc[0][cf] = __builtin_amdgcn_mfma_f32_16x16x32_f16(af[0][ksl], b, acc[0][cf], 0, 0, 0);
                acc[1][cf] = __builtin_amdgcn_mfma_f32_16x16x32_f16(af[1][ksl], b, acc[1][cf], 0, 0, 0);
            }
        }
        __builtin_amdgcn_s_setprio(0);

        if (s < 64) {
            // phase 0: exact online (max u, Z); rescale only on improve; skip far groups
#pragma unroll
            for (int fr = 0; fr < 2; ++fr)
#pragma unroll
            for (int reg = 0; reg < 4; ++reg) {
                const int ri = fr * 4 + reg;
                const float u0 = acc[fr][0][reg];
                const float u1 = acc[fr][1][reg];
                const float u2 = acc[fr][2][reg];
                const float u3 = acc[fr][3][reg];
                const float mloc = fmaxf(fmaxf(u0, u1), fmaxf(u2, u3));
                float m = pmx[ri];
                if (mloc > m - USKIP) {   // dropped terms < e^-17, Z >= 1
                    if (mloc > m) { pZ[ri] *= __expf(2.0f * (m - mloc)); m = mloc; pmx[ri] = m; }
                    pZ[ri] += __expf(2.0f * (u0 - m)) + __expf(2.0f * (u1 - m))
                            + __expf(2.0f * (u2 - m)) + __expf(2.0f * (u3 - m));
                }
            }
        } else {
            // phase 1: u bitwise identical to phase 0 (same init, same MFMA chain)
            float sp[4] = {0.f, 0.f, 0.f, 0.f};
#pragma unroll
            for (int fr = 0; fr < 2; ++fr)
#pragma unroll
            for (int reg = 0; reg < 4; ++reg) {
                const int ri = fr * 4 + reg;
                const float m = pmx[ri], iz = pZ[ri];   // pZ holds 1/Z in phase 1
#pragma unroll
                for (int cf = 0; cf < 4; ++cf) {
                    const float u = acc[fr][cf][reg];
                    // candidates: ballot + prefix-popcount slots, fire-and-forget stores
                    const bool hit = (u >= m - UMARGIN);   // m = exact phase-0 row max
                    const unsigned long long mk = __ballot(hit);
                    if (mk) {                              // uniform branch, rare
                        const unsigned grp = (unsigned)((mk >> (lg * 16)) & 0xFFFFull);
                        const int slot = bcnt[ri] + __popc(grp & ((1u << lc) - 1u));
                        if (hit && slot < CAND_CAP) {
                            const int rg_ = row0 + w * 32 + fr * 16 + lg * 4 + reg;
                            cand_idx[(size_t)rg_ * CAND_CAP + slot] = nt * 64 + cf * 16 + lc;
                        }
                        bcnt[ri] += __popc(grp);
                    }
                    if (u >= m - USKIP) sp[cf] += __expf(2.0f * (u - m)) * iz;
                }
            }
#pragma unroll
            for (int cf = 0; cf < 4; ++cf) {   // sum across lg, then LDS accumulate
                float v = sp[cf];
                v += __shfl_xor(v, 16, 64);
                v += __shfl_xor(v, 32, 64);
                if (l < 16) atomicAdd(&Sl[nt * 64 + cf * 16 + l], v);
            }
        }

        if (s == 63) {
            // phase boundary: merge (max,Z) across the 16 lanes sharing each row; pZ := 1/Z
#pragma unroll
            for (int ri = 0; ri < 8; ++ri) {
                float m = pmx[ri], Zv = pZ[ri];
#pragma unroll
                for (int off = 1; off < 16; off <<= 1) {
                    const float mo = __shfl_xor(m, off, 64);
                    const float Zo = __shfl_xor(Zv, off, 64);
                    const float mn = fmaxf(m, mo);
                    Zv = Zv * __expf(2.0f * (m - mn)) + Zo * __expf(2.0f * (mo - mn));
                    m = mn;
                }
                pmx[ri] = m;
                pZ[ri] = 1.0f / Zv;
            }
        }

        __syncthreads();   // sole vmcnt drain: staging + eev issued a full phase ago
#pragma unroll
        for (int cf = 0; cf < 4; ++cf) eevc[cf] = eevn[cf];
    }

    // final: per-row candidate counts (plain stores; every row covered once)
    if (lc == 0) {
#pragma unroll
        for (int fr = 0; fr < 2; ++fr)
#pragma unroll
        for (int reg = 0; reg < 4; ++reg)
            cand_cnt[row0 + w * 32 + fr * 16 + lg * 4 + reg] = bcnt[fr * 4 + reg];
    }

    for (int i = tid; i < NCODES; i += 256)
        Spart[(size_t)blockIdx.x * NCODES + i] = Sl[i];
}

// ---------------- refine: exact fp64 argmin over candidates ----------------
__global__ __launch_bounds__(256)
void refine_kernel(const float* __restrict__ z, const float* __restrict__ emb,
                   const int* __restrict__ cand_cnt, const int* __restrict__ cand_idx,
                   float* __restrict__ out_zq, float* __restrict__ out_idx,
                   unsigned int* __restrict__ bincnt, float* __restrict__ rowD)
{
    const int tid = threadIdx.x;
    const int w = tid >> 6, l = tid & 63;
    const int row = blockIdx.x * 4 + w;
    const float4 zv = *(const float4*)(z + (size_t)row * DDIM + l * 4);
    const double z0 = zv.x, z1 = zv.y, z2 = zv.z, z3 = zv.w;
    const int craw = cand_cnt[row];
    const int cnt = craw < 1 ? 1 : (craw > CAND_CAP ? CAND_CAP : craw);
    double dmin = 1e300; int kmin = 0;
    for (int c = 0; c < cnt; ++c) {
        int k = (craw < 1) ? 0 : cand_idx[(size_t)row * CAND_CAP + c];
        k &= (NCODES - 1);
        const float4 ev = *(const float4*)(emb + (size_t)k * DDIM + l * 4);
        const double t0 = z0 - ev.x, t1 = z1 - ev.y, t2 = z2 - ev.z, t3 = z3 - ev.w;
        double s = t0 * t0 + t1 * t1 + t2 * t2 + t3 * t3;
#pragma unroll
        for (int off = 1; off < 64; off <<= 1) s += __shfl_xor(s, off, 64);
        if (s < dmin || (s == dmin && k < kmin)) { dmin = s; kmin = k; }
    }
    const float4 bv = *(const float4*)(emb + (size_t)kmin * DDIM + l * 4);
    *(float4*)(out_zq + (size_t)row * DDIM + l * 4) = bv;   // z + sg(zq - z) == zq
    if (l == 0) {
        out_idx[row] = (float)kmin;
        atomicAdd(&bincnt[kmin], 1u);
        rowD[row] = (float)dmin;                             // dmin == ||z - zq||^2
    }
}

// ---------------- reductions ----------------
__global__ __launch_bounds__(256)
void reduce1_kernel(const float* __restrict__ Spart, const unsigned int* __restrict__ bincnt,
                    const float* __restrict__ rowD,
                    double* __restrict__ te, double* __restrict__ tp, double* __restrict__ tm)
{
    const int k = blockIdx.x * 256 + threadIdx.x;   // grid 16 -> k < 4096
    double s = 0.0;
#pragma unroll 8
    for (int wg = 0; wg < 512; ++wg) s += (double)Spart[(size_t)wg * NCODES + k];
    const double avg = s * (1.0 / 65536.0);
    te[k] = avg * log(avg + 1e-10);
    const double ap = (double)bincnt[k] * (1.0 / 65536.0);
    tp[k] = ap * log(ap + 1e-10);
    double dm = 0.0;
#pragma unroll
    for (int j = 0; j < 16; ++j) dm += (double)rowD[k * 16 + j];
    tm[k] = dm;
}

__global__ __launch_bounds__(256)
void reduce2_kernel(const double* __restrict__ te, const double* __restrict__ tp,
                    const double* __restrict__ tm, float* __restrict__ out)
{
    __shared__ double sa[256], sb[256], sc[256];
    const int tid = threadIdx.x;
    double a = 0.0, b = 0.0, c = 0.0;
    for (int i = tid; i < NCODES; i += 256) { a += te[i]; b += tp[i]; c += tm[i]; }
    sa[tid] = a; sb[tid] = b; sc[tid] = c;
    __syncthreads();
    for (int s = 128; s > 0; s >>= 1) {
        if (tid < s) { sa[tid] += sa[tid + s]; sb[tid] += sb[tid + s]; sc[tid] += sc[tid + s]; }
        __syncthreads();
    }
    if (tid == 0) {
        const double entropy    = -sa[0];
        const double diversity  = log(4096.0) - entropy;
        const double perplexity = exp(-sb[0]);
        const double mse        = sc[0] * (1.0 / 16777216.0);
        const double vq         = 1.25 * mse + 0.1 * diversity;  // 0.25*c + e + 0.1*d, c==e
        out[16777216] = (float)vq;
        out[16777217] = (float)perplexity;
        out[16842754] = (float)diversity;
    }
}

extern "C" void kernel_launch(void* const* d_in, const int* in_sizes, int n_in,
                              void* d_out, int out_size, void* d_ws, size_t ws_size,
                              hipStream_t stream)
{
    const float* z   = (const float*)d_in[0];
    const float* emb = (const float*)d_in[1];
    float* out = (float*)d_out;
    char* ws = (char*)d_ws;
    if (ws_size < (size_t)WS_END) return;   // need ~17.4 MB scratch

    unsigned int* bincnt   = (unsigned int*)(ws + WS_BINCNT);
    int*          cand_cnt = (int*)(ws + WS_CANDCNT);
    float*        Spart    = (float*)(ws + WS_SPART);
    _Float16*     ef16     = (_Float16*)(ws + WS_EF16);
    float*        ee       = (float*)(ws + WS_EE);
    float*        rowD     = (float*)(ws + WS_ROWD);
    int*          cand_idx = (int*)(ws + WS_CANDIDX);
    double*       te       = (double*)(ws + WS_TE);
    double*       tp       = (double*)(ws + WS_TP);
    double*       tm       = (double*)(ws + WS_CANDIDX);  // cand_idx dead after refine

    hipMemsetAsync(d_ws, 0, WS_ZERO_END, stream);   // bincnt only (16 KB)
    hipLaunchKernelGGL(prep_kernel, dim3(NCODES / 4), dim3(256), 0, stream, emb, ef16, ee);
    hipLaunchKernelGGL(sweep_fused_kernel, dim3(NROWS / 128), dim3(256), 0, stream,
                       z, ef16, ee, Spart, cand_cnt, cand_idx);
    hipLaunchKernelGGL(refine_kernel, dim3(NROWS / 4), dim3(256), 0, stream,
                       z, emb, cand_cnt, cand_idx, out, out + 16777218, bincnt, rowD);
    hipLaunchKernelGGL(reduce1_kernel, dim3(16), dim3(256), 0, stream, Spart, bincnt, rowD, te, tp, tm);
    hipLaunchKernelGGL(reduce2_kernel, dim3(1), dim3(256), 0, stream, te, tp, tm, out);
}

// Round 12
// 427.473 us; speedup vs baseline: 1.3517x; 1.0632x over previous
//
#include <hip/hip_runtime.h>
#include <cstdint>
#include <cstddef>

// VQ-VAE vector quantizer forward, MI355X.
// B=65536 rows, K=4096 codes, D=256.
// Outputs (flat float32): z_q_st[B*D] | vq_loss | perplexity | indices[B] | diversity_loss

#define NROWS     65536
#define NCODES    4096
#define DDIM      256
#define CAND_CAP  24
#define UMARGIN   1.0f    // u-space: d-margin 2.0 / 2
#define USKIP     8.5f    // u-space: d-skip 17 / 2 (dropped soft terms < e^-17, Z>=1)

typedef _Float16 half8 __attribute__((ext_vector_type(8)));
typedef _Float16 half4 __attribute__((ext_vector_type(4)));
typedef float    f32x4 __attribute__((ext_vector_type(4)));

// ---- workspace layout (bytes) ----
#define WS_BINCNT   0u          // 4096*4    = 16384    (zeroed)
#define WS_ZERO_END 16384u
#define WS_CANDCNT  16384u      // 65536*4   = 262144   (plain-written by sweep, no zero)
#define WS_SPART    278528u     // 512*4096*4 = 8388608 (fully written by sweep)
#define WS_EF16     8667136u    // 4096*256*2 = 2097152
#define WS_EE       10764288u   // 4096*4     = 16384
#define WS_ROWD     10780672u   // 65536*4    = 262144
#define WS_CANDIDX  11042816u   // 65536*24*4 = 6291456 (aliased as tm[4096] dbl after refine)
#define WS_TE       17334272u   // 4096*8     = 32768
#define WS_TP       17367040u   // 4096*8     = 32768
#define WS_END      17399808u

__device__ __forceinline__ void gload_lds16(const void* g, void* lds) {
    __builtin_amdgcn_global_load_lds(
        (const __attribute__((address_space(1))) unsigned int*)g,
        (__attribute__((address_space(3))) unsigned int*)lds, 16, 0, 0);
}

// ---------------- prep (embedding only): fp32 -> fp16 copy + row norms ----------------
__global__ __launch_bounds__(256)
void prep_kernel(const float* __restrict__ src, _Float16* __restrict__ dst,
                 float* __restrict__ norms)
{
    const int tid = threadIdx.x;
    const int w = tid >> 6, l = tid & 63;
    const int row = blockIdx.x * 4 + w;
    const float4 v = *(const float4*)(src + (size_t)row * DDIM + l * 4);
    half4 h;
    h[0] = (_Float16)v.x; h[1] = (_Float16)v.y;
    h[2] = (_Float16)v.z; h[3] = (_Float16)v.w;
    *(half4*)(dst + (size_t)row * DDIM + l * 4) = h;
    double s = (double)v.x * v.x + (double)v.y * v.y
             + (double)v.z * v.z + (double)v.w * v.w;
#pragma unroll
    for (int off = 1; off < 64; off <<= 1) s += __shfl_xor(s, off, 64);
    if (l == 0) norms[row] = (float)s;
}

// ---------------- fused two-phase distance sweep, double-buffered ----------------
// r7 geometry: 4 waves, wave w owns rows w*32..+31 for ALL codes (no cross-wave
// row sharing -> single candidate list per row, in-wave softmax merge only).
// B: 64-code x K=256 sub-tiles, 2 x 32 KB LDS dbuf, FRAGMENT-MAJOR
// (lane-linear conflict-free ds_read_b128; staged via global_load_lds with
// pre-permuted per-lane global source, rule #21).
// u-space accumulator init (acc = -0.5*||e||^2, MFMA emits u = -d'/2 -> no
// epilogue fma), eev prefetched one step ahead (no mid-loop vmem waits),
// ballot candidates (CAP 24, prefix-popcount slots, zero atomics).
// NO setprio: m190 A/B shows setprio hurts barrier-synced lockstep loops.
// Phase 0 (s 0..63): exact online (max u, Z), defer-rescale, skip-far exp.
// Phase 1 (s 64..127): u bitwise identical (same init + same MFMA chain);
// soft partials into LDS Sl (group-max-guarded exps); candidate shortlist.
__global__ __launch_bounds__(256, 2)
void sweep_fused_kernel(const float* __restrict__ z, const _Float16* __restrict__ ef,
                        const float* __restrict__ ee, float* __restrict__ Spart,
                        int* __restrict__ cand_cnt, int* __restrict__ cand_idx)
{
    __shared__ _Float16 Bl[2][64 * 256];   // 2 x 32 KB, fragment-major
    __shared__ float Sl[NCODES];           // 16 KB soft accumulator

    const int tid = threadIdx.x;
    const int w = tid >> 6, l = tid & 63;
    const int lg = l >> 4, lc = l & 15;
    const int row0 = blockIdx.x * 128;

    // A fragments: row = row0 + w*32 + fr*16 + lc, k = ksl*32 + lg*8 .. +8 (f32 -> f16)
    half8 af[2][8];
#pragma unroll
    for (int fr = 0; fr < 2; ++fr)
#pragma unroll
    for (int ksl = 0; ksl < 8; ++ksl) {
        const float* zp = z + (size_t)(row0 + w * 32 + fr * 16 + lc) * DDIM + ksl * 32 + lg * 8;
        const float4 v0 = *(const float4*)zp;
        const float4 v1 = *(const float4*)(zp + 4);
        half8 h;
        h[0] = (_Float16)v0.x; h[1] = (_Float16)v0.y; h[2] = (_Float16)v0.z; h[3] = (_Float16)v0.w;
        h[4] = (_Float16)v1.x; h[5] = (_Float16)v1.y; h[6] = (_Float16)v1.z; h[7] = (_Float16)v1.w;
        af[fr][ksl] = h;
    }

    for (int i = tid; i < NCODES; i += 256) Sl[i] = 0.0f;

    // staging: instr it_g = w*8+it = slot (ksl=it_g>>2, cf=it_g&3); lane l fetches
    // global code cf*16+lc at kbytes ksl*64+lg*16 -> LDS it_g*1024 + l*16 (linear).
    int soff[8];
#pragma unroll
    for (int it = 0; it < 8; ++it) {
        const int it_g = w * 8 + it;
        const int ksl = it_g >> 2, cf = it_g & 3;
        soff[it] = (cf * 16 + lc) * 512 + ksl * 64 + lg * 16;
    }
    const char* efb = (const char*)ef;
    char* blb = (char*)&Bl[0][0];

    float pmx[8], pZ[8];
#pragma unroll
    for (int i = 0; i < 8; ++i) { pmx[i] = -1e30f; pZ[i] = 0.0f; }
    int bcnt[8];
#pragma unroll
    for (int i = 0; i < 8; ++i) bcnt[i] = 0;

    // prologue: eev for tile 0 + stage tile 0 into buffer 0
    float eevc[4];
#pragma unroll
    for (int cf = 0; cf < 4; ++cf) eevc[cf] = ee[cf * 16 + lc];
#pragma unroll
    for (int it = 0; it < 8; ++it)
        gload_lds16(efb + soff[it], blb + (w * 8 + it) * 1024);
    __syncthreads();

    for (int s = 0; s < 128; ++s) {
        const int cur = s & 1;
        const int nt = s & 63;
        const int nnt = (s + 1) & 63;

        // next-step eev: issued now, consumed after the barrier (never waited mid-loop)
        float eevn[4];
#pragma unroll
        for (int cf = 0; cf < 4; ++cf) eevn[cf] = ee[nnt * 64 + cf * 16 + lc];

        if (s < 127) {                      // stage next sub-tile into other buffer
            const char* src = efb + ((size_t)nnt << 15);
            char* dst = blb + (cur ^ 1) * 32768;
#pragma unroll
            for (int it = 0; it < 8; ++it)
                gload_lds16(src + soff[it], dst + (w * 8 + it) * 1024);
        }

        // acc init: -0.5*||e||^2  ->  MFMA output u = z.e - ||e||^2/2 = -d'/2
        f32x4 acc[2][4];
#pragma unroll
        for (int cf = 0; cf < 4; ++cf) {
            const float eh = -0.5f * eevc[cf];
            acc[0][cf] = (f32x4){eh, eh, eh, eh};
            acc[1][cf] = (f32x4){eh, eh, eh, eh};
        }

        // lane-linear B reads (conflict-free), immediate offsets
        const char* bb = blb + cur * 32768 + (l << 4);
#pragma unroll
        for (int ksl = 0; ksl < 8; ++ksl) {
#pragma unroll
            for (int cf = 0; cf < 4; ++cf) {
                const half8 b = *(const half8*)(bb + (ksl * 4 + cf) * 1024);
                acc[0][cf] = __builtin_amdgcn_mfma_f32_16x16x32_f16(af[0][ksl], b, acc[0][cf], 0, 0, 0);
                acc[1][cf] = __builtin_amdgcn_mfma_f32_16x16x32_f16(af[1][ksl], b, acc[1][cf], 0, 0, 0);
            }
        }

        if (s < 64) {
            // phase 0: exact online (max u, Z); rescale only on improve; skip far groups
#pragma unroll
            for (int fr = 0; fr < 2; ++fr)
#pragma unroll
            for (int reg = 0; reg < 4; ++reg) {
                const int ri = fr * 4 + reg;
                const float u0 = acc[fr][0][reg];
                const float u1 = acc[fr][1][reg];
                const float u2 = acc[fr][2][reg];
                const float u3 = acc[fr][3][reg];
                const float mloc = fmaxf(fmaxf(u0, u1), fmaxf(u2, u3));
                float m = pmx[ri];
                if (mloc > m - USKIP) {   // dropped terms < e^-17, Z >= 1
                    if (mloc > m) { pZ[ri] *= __expf(2.0f * (m - mloc)); m = mloc; pmx[ri] = m; }
                    pZ[ri] += __expf(2.0f * (u0 - m)) + __expf(2.0f * (u1 - m))
                            + __expf(2.0f * (u2 - m)) + __expf(2.0f * (u3 - m));
                }
            }
        } else {
            // phase 1: u bitwise identical to phase 0 (same init, same MFMA chain)
            float sp[4] = {0.f, 0.f, 0.f, 0.f};
#pragma unroll
            for (int fr = 0; fr < 2; ++fr)
#pragma unroll
            for (int reg = 0; reg < 4; ++reg) {
                const int ri = fr * 4 + reg;
                const float m = pmx[ri], iz = pZ[ri];   // pZ holds 1/Z in phase 1
                const float u0 = acc[fr][0][reg];
                const float u1 = acc[fr][1][reg];
                const float u2 = acc[fr][2][reg];
                const float u3 = acc[fr][3][reg];
                // candidates: ballot + prefix-popcount slots (unconditional per cf —
                // cross-lane slot consistency requires uniform participation)
#pragma unroll
                for (int cf = 0; cf < 4; ++cf) {
                    const float u = acc[fr][cf][reg];
                    const bool hit = (u >= m - UMARGIN);   // m = exact phase-0 row max
                    const unsigned long long mk = __ballot(hit);
                    if (mk) {                              // uniform branch, rare
                        const unsigned grp = (unsigned)((mk >> (lg * 16)) & 0xFFFFull);
                        const int slot = bcnt[ri] + __popc(grp & ((1u << lc) - 1u));
                        if (hit && slot < CAND_CAP) {
                            const int rg_ = row0 + w * 32 + fr * 16 + lg * 4 + reg;
                            cand_idx[(size_t)rg_ * CAND_CAP + slot] = nt * 64 + cf * 16 + lc;
                        }
                        bcnt[ri] += __popc(grp);
                    }
                }
                // soft partials: one group-max guard instead of 4 per-element cmps
                // (per-lane divergence safe; dropped terms < e^-17 with Z >= 1)
                const float umax = fmaxf(fmaxf(u0, u1), fmaxf(u2, u3));
                if (umax >= m - USKIP) {
                    sp[0] += __expf(2.0f * (u0 - m)) * iz;
                    sp[1] += __expf(2.0f * (u1 - m)) * iz;
                    sp[2] += __expf(2.0f * (u2 - m)) * iz;
                    sp[3] += __expf(2.0f * (u3 - m)) * iz;
                }
            }
#pragma unroll
            for (int cf = 0; cf < 4; ++cf) {   // sum across lg, then LDS accumulate
                float v = sp[cf];
                v += __shfl_xor(v, 16, 64);
                v += __shfl_xor(v, 32, 64);
                if (l < 16) atomicAdd(&Sl[nt * 64 + cf * 16 + l], v);
            }
        }

        if (s == 63) {
            // phase boundary: merge (max,Z) across the 16 lanes sharing each row; pZ := 1/Z
#pragma unroll
            for (int ri = 0; ri < 8; ++ri) {
                float m = pmx[ri], Zv = pZ[ri];
#pragma unroll
                for (int off = 1; off < 16; off <<= 1) {
                    const float mo = __shfl_xor(m, off, 64);
                    const float Zo = __shfl_xor(Zv, off, 64);
                    const float mn = fmaxf(m, mo);
                    Zv = Zv * __expf(2.0f * (m - mn)) + Zo * __expf(2.0f * (mo - mn));
                    m = mn;
                }
                pmx[ri] = m;
                pZ[ri] = 1.0f / Zv;
            }
        }

        __syncthreads();   // sole vmcnt drain: staging + eev issued a full phase ago
#pragma unroll
        for (int cf = 0; cf < 4; ++cf) eevc[cf] = eevn[cf];
    }

    // final: per-row candidate counts (plain stores; every row covered once)
    if (lc == 0) {
#pragma unroll
        for (int fr = 0; fr < 2; ++fr)
#pragma unroll
        for (int reg = 0; reg < 4; ++reg)
            cand_cnt[row0 + w * 32 + fr * 16 + lg * 4 + reg] = bcnt[fr * 4 + reg];
    }

    for (int i = tid; i < NCODES; i += 256)
        Spart[(size_t)blockIdx.x * NCODES + i] = Sl[i];
}

// ---------------- refine: exact fp64 argmin over candidates ----------------
__global__ __launch_bounds__(256)
void refine_kernel(const float* __restrict__ z, const float* __restrict__ emb,
                   const int* __restrict__ cand_cnt, const int* __restrict__ cand_idx,
                   float* __restrict__ out_zq, float* __restrict__ out_idx,
                   unsigned int* __restrict__ bincnt, float* __restrict__ rowD)
{
    const int tid = threadIdx.x;
    const int w = tid >> 6, l = tid & 63;
    const int row = blockIdx.x * 4 + w;
    const float4 zv = *(const float4*)(z + (size_t)row * DDIM + l * 4);
    const double z0 = zv.x, z1 = zv.y, z2 = zv.z, z3 = zv.w;
    const int craw = cand_cnt[row];
    const int cnt = craw < 1 ? 1 : (craw > CAND_CAP ? CAND_CAP : craw);
    double dmin = 1e300; int kmin = 0;
    for (int c = 0; c < cnt; ++c) {
        int k = (craw < 1) ? 0 : cand_idx[(size_t)row * CAND_CAP + c];
        k &= (NCODES - 1);
        const float4 ev = *(const float4*)(emb + (size_t)k * DDIM + l * 4);
        const double t0 = z0 - ev.x, t1 = z1 - ev.y, t2 = z2 - ev.z, t3 = z3 - ev.w;
        double s = t0 * t0 + t1 * t1 + t2 * t2 + t3 * t3;
#pragma unroll
        for (int off = 1; off < 64; off <<= 1) s += __shfl_xor(s, off, 64);
        if (s < dmin || (s == dmin && k < kmin)) { dmin = s; kmin = k; }
    }
    const float4 bv = *(const float4*)(emb + (size_t)kmin * DDIM + l * 4);
    *(float4*)(out_zq + (size_t)row * DDIM + l * 4) = bv;   // z + sg(zq - z) == zq
    if (l == 0) {
        out_idx[row] = (float)kmin;
        atomicAdd(&bincnt[kmin], 1u);
        rowD[row] = (float)dmin;                             // dmin == ||z - zq||^2
    }
}

// ---------------- reductions ----------------
__global__ __launch_bounds__(256)
void reduce1_kernel(const float* __restrict__ Spart, const unsigned int* __restrict__ bincnt,
                    const float* __restrict__ rowD,
                    double* __restrict__ te, double* __restrict__ tp, double* __restrict__ tm)
{
    const int k = blockIdx.x * 256 + threadIdx.x;   // grid 16 -> k < 4096
    double s = 0.0;
#pragma unroll 8
    for (int wg = 0; wg < 512; ++wg) s += (double)Spart[(size_t)wg * NCODES + k];
    const double avg = s * (1.0 / 65536.0);
    te[k] = avg * log(avg + 1e-10);
    const double ap = (double)bincnt[k] * (1.0 / 65536.0);
    tp[k] = ap * log(ap + 1e-10);
    double dm = 0.0;
#pragma unroll
    for (int j = 0; j < 16; ++j) dm += (double)rowD[k * 16 + j];
    tm[k] = dm;
}

__global__ __launch_bounds__(256)
void reduce2_kernel(const double* __restrict__ te, const double* __restrict__ tp,
                    const double* __restrict__ tm, float* __restrict__ out)
{
    __shared__ double sa[256], sb[256], sc[256];
    const int tid = threadIdx.x;
    double a = 0.0, b = 0.0, c = 0.0;
    for (int i = tid; i < NCODES; i += 256) { a += te[i]; b += tp[i]; c += tm[i]; }
    sa[tid] = a; sb[tid] = b; sc[tid] = c;
    __syncthreads();
    for (int s = 128; s > 0; s >>= 1) {
        if (tid < s) { sa[tid] += sa[tid + s]; sb[tid] += sb[tid + s]; sc[tid] += sc[tid + s]; }
        __syncthreads();
    }
    if (tid == 0) {
        const double entropy    = -sa[0];
        const double diversity  = log(4096.0) - entropy;
        const double perplexity = exp(-sb[0]);
        const double mse        = sc[0] * (1.0 / 16777216.0);
        const double vq         = 1.25 * mse + 0.1 * diversity;  // 0.25*c + e + 0.1*d, c==e
        out[16777216] = (float)vq;
        out[16777217] = (float)perplexity;
        out[16842754] = (float)diversity;
    }
}

extern "C" void kernel_launch(void* const* d_in, const int* in_sizes, int n_in,
                              void* d_out, int out_size, void* d_ws, size_t ws_size,
                              hipStream_t stream)
{
    const float* z   = (const float*)d_in[0];
    const float* emb = (const float*)d_in[1];
    float* out = (float*)d_out;
    char* ws = (char*)d_ws;
    if (ws_size < (size_t)WS_END) return;   // need ~17.4 MB scratch

    unsigned int* bincnt   = (unsigned int*)(ws + WS_BINCNT);
    int*          cand_cnt = (int*)(ws + WS_CANDCNT);
    float*        Spart    = (float*)(ws + WS_SPART);
    _Float16*     ef16     = (_Float16*)(ws + WS_EF16);
    float*        ee       = (float*)(ws + WS_EE);
    float*        rowD     = (float*)(ws + WS_ROWD);
    int*          cand_idx = (int*)(ws + WS_CANDIDX);
    double*       te       = (double*)(ws + WS_TE);
    double*       tp       = (double*)(ws + WS_TP);
    double*       tm       = (double*)(ws + WS_CANDIDX);  // cand_idx dead after refine

    hipMemsetAsync(d_ws, 0, WS_ZERO_END, stream);   // bincnt only (16 KB)
    hipLaunchKernelGGL(prep_kernel, dim3(NCODES / 4), dim3(256), 0, stream, emb, ef16, ee);
    hipLaunchKernelGGL(sweep_fused_kernel, dim3(NROWS / 128), dim3(256), 0, stream,
                       z, ef16, ee, Spart, cand_cnt, cand_idx);
    hipLaunchKernelGGL(refine_kernel, dim3(NROWS / 4), dim3(256), 0, stream,
                       z, emb, cand_cnt, cand_idx, out, out + 16777218, bincnt, rowD);
    hipLaunchKernelGGL(reduce1_kernel, dim3(16), dim3(256), 0, stream, Spart, bincnt, rowD, te, tp, tm);
    hipLaunchKernelGGL(reduce2_kernel, dim3(1), dim3(256), 0, stream, te, tp, tm, out);
}